// Round 13
// baseline (1696.582 us; speedup 1.0000x reference)
//
#include <hip/hip_runtime.h>
#include <cmath>

#define GS_LOOP(i, n) for (int i = blockIdx.x * blockDim.x + threadIdx.x; i < (n); i += gridDim.x * blockDim.x)

constexpr int NUSERS = 50000;
constexpr int NNODES = 100000;
constexpr int EMBD   = 128;
constexpr int NEDGE  = 2000000;
constexpr int NSCAN  = (NNODES + 1023) / 1024;   // 98
constexpr int ECAP   = 32;                        // LDS-stashed edges per node (P(deg>32)~0.4%)

typedef float          v4f   __attribute__((ext_vector_type(4)));
typedef unsigned short v4u16 __attribute__((ext_vector_type(4)));

__device__ __forceinline__ float bf2f(unsigned short u) {
  union { unsigned int i; float f; } v; v.i = ((unsigned int)u) << 16; return v.f;
}
__device__ __forceinline__ unsigned short f2bf(float x) {
  union { float f; unsigned int i; } v; v.f = x;
  unsigned int r = v.i + 0x7FFFu + ((v.i >> 16) & 1u);   // round to nearest even
  return (unsigned short)(r >> 16);
}
// tanh(y/||.||) with nvs = 2*log2e/||.|| : 1 - 2/(exp2(y*nvs)+1)
__device__ __forceinline__ float tnh(unsigned short u, float nvs) {
  const float E = exp2f(bf2f(u) * nvs);
  return 1.f - 2.f * __builtin_amdgcn_rcpf(E + 1.f);
}
constexpr float TSCL = 2.f * 1.44269504088896f;   // 2*log2(e)

// ---------------- init (row-oriented): ego0 + Pb0 + nv0 in one read ----------------
__global__ __launch_bounds__(256) void init_k(const float4* __restrict__ ue4,
                                              const float4* __restrict__ ie4,
                                              float4* __restrict__ ego0,
                                              ushort4* __restrict__ Pb0,
                                              float* __restrict__ nv0) {
  const int j = threadIdx.x & 31;
  const int u = blockIdx.x * 8 + (threadIdx.x >> 5);
  if (u >= NNODES) return;
  const float4 y = (u < NUSERS) ? ue4[(size_t)u * 32 + j]
                                : ie4[(size_t)(u - NUSERS) * 32 + j];
  ego0[(size_t)u * 32 + j] = y;
  Pb0[(size_t)u * 32 + j] = make_ushort4(f2bf(y.x), f2bf(y.y), f2bf(y.z), f2bf(y.w));
  float ss = y.x * y.x + y.y * y.y + y.z * y.z + y.w * y.w;
  ss += __shfl_xor(ss, 1, 64);
  ss += __shfl_xor(ss, 2, 64);
  ss += __shfl_xor(ss, 4, 64);                  // 8-lane factor-group reduce
  const float inv = 1.f / fmaxf(sqrtf(ss), 1e-12f);
  if ((j & 7) == 0) nv0[u * 4 + (j >> 3)] = TSCL * inv;
}

// ---------------- CSR build ----------------
__global__ void hist_k(const int* __restrict__ h, int* __restrict__ counts) {
  GS_LOOP(e, NEDGE) atomicAdd(&counts[h[e]], 1);
}

// hierarchical scan: per-block inclusive scan + block sums
__global__ __launch_bounds__(1024) void scan1_k(const int* __restrict__ counts,
                                                int* __restrict__ part,
                                                int* __restrict__ bsum) {
  __shared__ int wsum[16];
  const int tid = threadIdx.x, lane = tid & 63, wid = tid >> 6;
  const int i = blockIdx.x * 1024 + tid;
  int v = (i < NNODES) ? counts[i] : 0;
  #pragma unroll
  for (int off = 1; off < 64; off <<= 1) {
    int y = __shfl_up(v, off, 64);
    if (lane >= off) v += y;
  }
  if (lane == 63) wsum[wid] = v;
  __syncthreads();
  if (wid == 0) {
    int w = (lane < 16) ? wsum[lane] : 0;
    #pragma unroll
    for (int off = 1; off < 16; off <<= 1) {
      int y = __shfl_up(w, off, 64);
      if (lane >= off) w += y;
    }
    if (lane < 16) wsum[lane] = w;
  }
  __syncthreads();
  const int incl = v + (wid ? wsum[wid - 1] : 0);
  if (i < NNODES) part[i] = incl;
  if (tid == 1023) bsum[blockIdx.x] = incl;
}

__global__ __launch_bounds__(128) void scan2_k(const int* __restrict__ bsum,
                                               int* __restrict__ boff) {
  __shared__ int s0[128], s1[128];
  const int tid = threadIdx.x;
  s0[tid] = (tid < NSCAN) ? bsum[tid] : 0;
  __syncthreads();
  int* a = s0; int* b = s1;
  for (int off = 1; off < 128; off <<= 1) {
    const int val = a[tid] + ((tid >= off) ? a[tid - off] : 0);
    b[tid] = val;
    __syncthreads();
    int* tmp = a; a = b; b = tmp;
  }
  boff[tid] = (tid == 0) ? 0 : a[tid - 1];
}

// also derives pass-0 d_inv analytically: softmax(ones)=0.25 -> deg0 = 0.25*count
__global__ __launch_bounds__(1024) void scan3_k(const int* __restrict__ part,
                                                const int* __restrict__ boff,
                                                const int* __restrict__ counts,
                                                int* __restrict__ row_ptr,
                                                float* __restrict__ dv0) {
  const int i = blockIdx.x * 1024 + threadIdx.x;
  if (i < NNODES) {
    row_ptr[i + 1] = part[i] + boff[blockIdx.x];
    const float d = rsqrtf(fmaxf(0.25f * (float)counts[i], 1e-12f));
    v4f w = {d, d, d, d};
    *((v4f*)dv0 + i) = w;
  }
  if (i == 0) row_ptr[0] = 0;
}

// edge identity irrelevant downstream (A lives in CSR order): store only t
__global__ void fill_k(const int* __restrict__ h, const int* __restrict__ t,
                       const int* __restrict__ row_ptr, int* __restrict__ cur,
                       int* __restrict__ csr_t) {
  GS_LOOP(e, NEDGE) {
    int u = h[e];
    int pos = row_ptr[u] + atomicAdd(&cur[u], 1);
    csr_t[pos] = t[e];
  }
}

// ---------------- per-pass: softmax(A)->c (bf16, csr order) + d_inv, 16 lanes/node ----------------
__global__ __launch_bounds__(256) void deg_sm_k(const float* __restrict__ A,
                                                const int* __restrict__ row_ptr,
                                                unsigned short* __restrict__ c,
                                                float* __restrict__ dv) {
  const float4* A4 = (const float4*)A;
  ushort4* c4 = (ushort4*)c;
  const int g = threadIdx.x >> 4;
  const int lane16 = threadIdx.x & 15;
  const int u = blockIdx.x * 16 + g;
  if (u >= NNODES) return;
  const int beg = row_ptr[u], end = row_ptr[u + 1];
  float4 acc = make_float4(0.f, 0.f, 0.f, 0.f);
  for (int p = beg + lane16; p < end; p += 16) {
    float4 a = A4[p];
    float m = fmaxf(fmaxf(a.x, a.y), fmaxf(a.z, a.w));
    float e0 = __expf(a.x - m), e1 = __expf(a.y - m);
    float e2 = __expf(a.z - m), e3 = __expf(a.w - m);
    float inv = 1.f / (e0 + e1 + e2 + e3);
    float4 s = make_float4(e0 * inv, e1 * inv, e2 * inv, e3 * inv);
    c4[p] = make_ushort4(f2bf(s.x), f2bf(s.y), f2bf(s.z), f2bf(s.w));
    acc.x += s.x; acc.y += s.y; acc.z += s.z; acc.w += s.w;
  }
  #pragma unroll
  for (int m = 1; m < 16; m <<= 1) {
    acc.x += __shfl_xor(acc.x, m, 64);
    acc.y += __shfl_xor(acc.y, m, 64);
    acc.z += __shfl_xor(acc.z, m, 64);
    acc.w += __shfl_xor(acc.w, m, 64);
  }
  if (lane16 == 0)
    ((float4*)dv)[u] = make_float4(rsqrtf(fmaxf(acc.x, 1e-12f)),
                                   rsqrtf(fmaxf(acc.y, 1e-12f)),
                                   rsqrtf(fmaxf(acc.z, 1e-12f)),
                                   rsqrtf(fmaxf(acc.w, 1e-12f)));
}

// ---------------- fused propagate + score update (wave per node, bf16 gathers) ----------------
// Loop 1 stashes gathered rows in wave-private LDS; loop 2 reads them back (no 2nd gather)
// and computes tanh on the fly from the per-node chunk-norm scale table nv.
// MODE: 0 = score only; 1 = score + write Q(f32) + Pb1/nv1 tables; 2 = mean output to o1
// FIRST: pass 0 (A implicitly 1.0, scores uniform 0.25, c never read)
template <int MODE, bool FIRST>
__global__ __launch_bounds__(256) void prop_k(
    const ushort4* __restrict__ Pb4, float4* __restrict__ Q4,
    const float* __restrict__ dv_in, const float* __restrict__ nv_in,
    const int* __restrict__ row_ptr, const int* __restrict__ csr_t,
    const unsigned short* __restrict__ c, float* __restrict__ A,
    const float4* __restrict__ e0_4, const float4* __restrict__ e1_4,
    float4* __restrict__ o1_4, ushort4* __restrict__ Pb1w,
    float* __restrict__ nv1w) {
  __shared__ ushort4 stash[4 * ECAP * 32];       // 32 KB: 4 waves x ECAP edges x 32 cols
  const int u = blockIdx.x * 4 + (threadIdx.x >> 6);
  const int l = threadIdx.x & 63;
  const int half = l >> 5;     // which of 2 edges per iteration
  const int j = l & 31;        // float4 column
  const int f = j >> 3;        // factor
  const int wbase = (threadIdx.x >> 6) * (ECAP * 32);
  const int beg = row_ptr[u], end = row_ptr[u + 1];

  // loop 1: x[u] = d_inv[u] * sum_p c[p][f] * d_inv[t_p][f] * Pb[t_p]   (+ LDS stash)
  float4 acc = make_float4(0.f, 0.f, 0.f, 0.f);
  int p = beg + half;
  for (; p + 14 < end; p += 16) {              // manual unroll x8: 8 row gathers in flight
    const int t0 = csr_t[p],      t1 = csr_t[p + 2];
    const int t2 = csr_t[p + 4],  t3 = csr_t[p + 6];
    const int t4 = csr_t[p + 8],  t5 = csr_t[p + 10];
    const int t6 = csr_t[p + 12], t7 = csr_t[p + 14];
    const ushort4 y0 = Pb4[(size_t)t0 * 32 + j];
    const ushort4 y1 = Pb4[(size_t)t1 * 32 + j];
    const ushort4 y2 = Pb4[(size_t)t2 * 32 + j];
    const ushort4 y3 = Pb4[(size_t)t3 * 32 + j];
    const ushort4 y4 = Pb4[(size_t)t4 * 32 + j];
    const ushort4 y5 = Pb4[(size_t)t5 * 32 + j];
    const ushort4 y6 = Pb4[(size_t)t6 * 32 + j];
    const ushort4 y7 = Pb4[(size_t)t7 * 32 + j];
    if (MODE != 2) {                           // stash for loop 2 (wave-private, no sync)
      const int sl = p - beg;
      if (sl      < ECAP) stash[wbase + (sl     ) * 32 + j] = y0;
      if (sl + 2  < ECAP) stash[wbase + (sl + 2 ) * 32 + j] = y1;
      if (sl + 4  < ECAP) stash[wbase + (sl + 4 ) * 32 + j] = y2;
      if (sl + 6  < ECAP) stash[wbase + (sl + 6 ) * 32 + j] = y3;
      if (sl + 8  < ECAP) stash[wbase + (sl + 8 ) * 32 + j] = y4;
      if (sl + 10 < ECAP) stash[wbase + (sl + 10) * 32 + j] = y5;
      if (sl + 12 < ECAP) stash[wbase + (sl + 12) * 32 + j] = y6;
      if (sl + 14 < ECAP) stash[wbase + (sl + 14) * 32 + j] = y7;
    }
    const float c0 = (FIRST ? 0.25f : bf2f(__builtin_nontemporal_load(c + (size_t)p * 4 + f)))        * dv_in[t0 * 4 + f];
    const float c1 = (FIRST ? 0.25f : bf2f(__builtin_nontemporal_load(c + (size_t)(p + 2) * 4 + f)))  * dv_in[t1 * 4 + f];
    const float c2 = (FIRST ? 0.25f : bf2f(__builtin_nontemporal_load(c + (size_t)(p + 4) * 4 + f)))  * dv_in[t2 * 4 + f];
    const float c3 = (FIRST ? 0.25f : bf2f(__builtin_nontemporal_load(c + (size_t)(p + 6) * 4 + f)))  * dv_in[t3 * 4 + f];
    const float c4_ = (FIRST ? 0.25f : bf2f(__builtin_nontemporal_load(c + (size_t)(p + 8) * 4 + f))) * dv_in[t4 * 4 + f];
    const float c5 = (FIRST ? 0.25f : bf2f(__builtin_nontemporal_load(c + (size_t)(p + 10) * 4 + f))) * dv_in[t5 * 4 + f];
    const float c6 = (FIRST ? 0.25f : bf2f(__builtin_nontemporal_load(c + (size_t)(p + 12) * 4 + f))) * dv_in[t6 * 4 + f];
    const float c7 = (FIRST ? 0.25f : bf2f(__builtin_nontemporal_load(c + (size_t)(p + 14) * 4 + f))) * dv_in[t7 * 4 + f];
    acc.x += c0 * bf2f(y0.x) + c1 * bf2f(y1.x) + c2 * bf2f(y2.x) + c3 * bf2f(y3.x)
           + c4_ * bf2f(y4.x) + c5 * bf2f(y5.x) + c6 * bf2f(y6.x) + c7 * bf2f(y7.x);
    acc.y += c0 * bf2f(y0.y) + c1 * bf2f(y1.y) + c2 * bf2f(y2.y) + c3 * bf2f(y3.y)
           + c4_ * bf2f(y4.y) + c5 * bf2f(y5.y) + c6 * bf2f(y6.y) + c7 * bf2f(y7.y);
    acc.z += c0 * bf2f(y0.z) + c1 * bf2f(y1.z) + c2 * bf2f(y2.z) + c3 * bf2f(y3.z)
           + c4_ * bf2f(y4.z) + c5 * bf2f(y5.z) + c6 * bf2f(y6.z) + c7 * bf2f(y7.z);
    acc.w += c0 * bf2f(y0.w) + c1 * bf2f(y1.w) + c2 * bf2f(y2.w) + c3 * bf2f(y3.w)
           + c4_ * bf2f(y4.w) + c5 * bf2f(y5.w) + c6 * bf2f(y6.w) + c7 * bf2f(y7.w);
  }
  for (; p < end; p += 2) {                    // tail
    const int tn = csr_t[p];
    const float cf = (FIRST ? 0.25f : bf2f(__builtin_nontemporal_load(c + (size_t)p * 4 + f))) * dv_in[tn * 4 + f];
    const ushort4 y = Pb4[(size_t)tn * 32 + j];
    if (MODE != 2) {
      const int sl = p - beg;
      if (sl < ECAP) stash[wbase + sl * 32 + j] = y;
    }
    acc.x += cf * bf2f(y.x); acc.y += cf * bf2f(y.y);
    acc.z += cf * bf2f(y.z); acc.w += cf * bf2f(y.w);
  }
  acc.x += __shfl_xor(acc.x, 32, 64);
  acc.y += __shfl_xor(acc.y, 32, 64);
  acc.z += __shfl_xor(acc.z, 32, 64);
  acc.w += __shfl_xor(acc.w, 32, 64);
  const float du = dv_in[u * 4 + f];
  const float4 x = make_float4(acc.x * du, acc.y * du, acc.z * du, acc.w * du);

  if (MODE == 2) {                             // final pass: write mean(e0,e1,x) to o1
    if (half == 0) {
      const v4f a = __builtin_nontemporal_load((const v4f*)e0_4 + (size_t)u * 32 + j);
      const v4f b = __builtin_nontemporal_load((const v4f*)e1_4 + (size_t)u * 32 + j);
      v4f r = {(a.x + b.x + x.x) * (1.f / 3.f), (a.y + b.y + x.y) * (1.f / 3.f),
               (a.z + b.z + x.z) * (1.f / 3.f), (a.w + b.w + x.w) * (1.f / 3.f)};
      __builtin_nontemporal_store(r, (v4f*)o1_4 + (size_t)u * 32 + j);
    }
    return;
  }
  if (MODE == 1 && half == 0) {
    v4f xq = {x.x, x.y, x.z, x.w};
    __builtin_nontemporal_store(xq, (v4f*)Q4 + (size_t)u * 32 + j);
    v4u16 pb = {f2bf(x.x), f2bf(x.y), f2bf(x.z), f2bf(x.w)};
    __builtin_nontemporal_store(pb, (v4u16*)Pb1w + (size_t)u * 32 + j);
  }

  // chunk l2-norm of x (8-lane factor group)
  float ss = x.x * x.x + x.y * x.y + x.z * x.z + x.w * x.w;
  ss += __shfl_xor(ss, 1, 64);
  ss += __shfl_xor(ss, 2, 64);
  ss += __shfl_xor(ss, 4, 64);
  const float inv = 1.f / fmaxf(sqrtf(ss), 1e-12f);
  const float4 xn = make_float4(x.x * inv, x.y * inv, x.z * inv, x.w * inv);
  if (MODE == 1 && half == 0 && (j & 7) == 0) nv1w[u * 4 + f] = TSCL * inv;

  // loop 2: A[p][f] += dot(xn, tanh(Pb[t]*ninv[t]))  -- rows from LDS stash
  int q = beg + half;
  for (; q + 2 < end; q += 4) {                // manual unroll x2
    const int t0 = csr_t[q], t1 = csr_t[q + 2];
    const int sl0 = q - beg, sl1 = sl0 + 2;
    const ushort4 b0 = (sl0 < ECAP) ? stash[wbase + sl0 * 32 + j] : Pb4[(size_t)t0 * 32 + j];
    const ushort4 b1 = (sl1 < ECAP) ? stash[wbase + sl1 * 32 + j] : Pb4[(size_t)t1 * 32 + j];
    const float n0 = nv_in[t0 * 4 + f], n1 = nv_in[t1 * 4 + f];
    float s0 = xn.x * tnh(b0.x, n0) + xn.y * tnh(b0.y, n0)
             + xn.z * tnh(b0.z, n0) + xn.w * tnh(b0.w, n0);
    float s1 = xn.x * tnh(b1.x, n1) + xn.y * tnh(b1.y, n1)
             + xn.z * tnh(b1.z, n1) + xn.w * tnh(b1.w, n1);
    #pragma unroll
    for (int m = 1; m < 8; m <<= 1) {
      s0 += __shfl_xor(s0, m, 64); s1 += __shfl_xor(s1, m, 64);
    }
    if ((j & 7) == 0) {
      if (FIRST) {
        A[(size_t)q * 4 + f] = 1.f + s0;
        A[(size_t)(q + 2) * 4 + f] = 1.f + s1;
      } else {
        A[(size_t)q * 4 + f] += s0;
        A[(size_t)(q + 2) * 4 + f] += s1;
      }
    }
  }
  for (; q < end; q += 2) {                    // tail
    const int tn = csr_t[q];
    const int sl = q - beg;
    const ushort4 tb = (sl < ECAP) ? stash[wbase + sl * 32 + j] : Pb4[(size_t)tn * 32 + j];
    const float nn = nv_in[tn * 4 + f];
    float s = xn.x * tnh(tb.x, nn) + xn.y * tnh(tb.y, nn)
            + xn.z * tnh(tb.z, nn) + xn.w * tnh(tb.w, nn);
    s += __shfl_xor(s, 1, 64);
    s += __shfl_xor(s, 2, 64);
    s += __shfl_xor(s, 4, 64);
    if ((j & 7) == 0) {
      if (FIRST) A[(size_t)q * 4 + f] = 1.f + s;
      else       A[(size_t)q * 4 + f] += s;
    }
  }
}

extern "C" void kernel_launch(void* const* d_in, const int* in_sizes, int n_in,
                              void* d_out, int out_size, void* d_ws, size_t ws_size,
                              hipStream_t stream) {
  const float* ue = (const float*)d_in[0];
  const float* ie = (const float*)d_in[1];
  const int* h = (const int*)d_in[2];
  const int* t = (const int*)d_in[3];
  float* out = (float*)d_out;
  char* ws = (char*)d_ws;

  size_t off = 0;
  auto alloc = [&](size_t bytes) -> void* {
    void* p = ws + off;
    off += (bytes + 255) & ~size_t(255);
    return p;
  };
  float* ego0  = (float*)alloc(sizeof(float) * (size_t)NNODES * EMBD);  // 51.2 MB
  float* ego1  = (float*)alloc(sizeof(float) * (size_t)NNODES * EMBD);  // 51.2 MB
  float* A     = (float*)alloc(sizeof(float) * 4 * (size_t)NEDGE);      // 32  MB (CSR order)
  unsigned short* c = (unsigned short*)alloc(sizeof(unsigned short) * 4 * (size_t)NEDGE); // 16 MB (bf16)
  float* dvA   = (float*)alloc(sizeof(float) * NNODES * 4);             // 1.6 MB (ping)
  float* dvB   = (float*)alloc(sizeof(float) * NNODES * 4);             // 1.6 MB (pong)
  int* row_ptr = (int*)alloc(sizeof(int) * (NNODES + 1));
  int* cur     = (int*)alloc(sizeof(int) * NNODES);
  int* part    = (int*)alloc(sizeof(int) * NNODES);
  int* bsum    = (int*)alloc(sizeof(int) * 128);
  int* boff    = (int*)alloc(sizeof(int) * 128);
  int* csr_t   = (int*)alloc(sizeof(int) * NEDGE);                      // 8 MB

  // bf16 gather table + norm-scale table live in d_out halves (Pb 25.6 MB + nv 1.6 MB each).
  // Layer-1 tables in o1 (dead by pass 3, which overwrites o1);
  // layer-2 tables in o2 (read during pass 3; o2 refilled by the final d2d copy).
  float* o1 = out;
  float* o2 = out + (size_t)NNODES * EMBD;
  ushort4* Pb0 = (ushort4*)o1;
  float*   nv0 = (float*)((char*)o1 + sizeof(unsigned short) * (size_t)NNODES * EMBD);
  ushort4* Pb1 = (ushort4*)o2;
  float*   nv1 = (float*)((char*)o2 + sizeof(unsigned short) * (size_t)NNODES * EMBD);

  // setup (once per call)
  init_k<<<(NNODES + 7) / 8, 256, 0, stream>>>((const float4*)ue, (const float4*)ie,
                                               (float4*)ego0, Pb0, nv0);
  hipMemsetAsync(cur, 0, sizeof(int) * NNODES, stream);
  hist_k<<<2048, 256, 0, stream>>>(h, cur);
  scan1_k<<<NSCAN, 1024, 0, stream>>>(cur, part, bsum);
  scan2_k<<<1, 128, 0, stream>>>(bsum, boff);
  scan3_k<<<NSCAN, 1024, 0, stream>>>(part, boff, cur, row_ptr, dvA);
  hipMemsetAsync(cur, 0, sizeof(int) * NNODES, stream);
  fill_k<<<2048, 256, 0, stream>>>(h, t, row_ptr, cur, csr_t);

  // pass 0: score (analytic softmax=0.25, dv from counts)  [layer-1 tables]
  // pass 1: deg_sm(A)->c,dvB; score + Q=ego1 + Pb1/nv1     [layer-1 tables]
  // pass 2: deg_sm(A)->c,dvA; score                        [layer-2 tables]
  // pass 3: deg_sm(A)->c,dvB; mean output -> o1            [layer-2 tables]
  prop_k<0, true><<<NNODES / 4, 256, 0, stream>>>(
      Pb0, (float4*)ego1, dvA, nv0, row_ptr, csr_t, c, A,
      (const float4*)ego0, (const float4*)ego1, (float4*)o1, Pb1, nv1);

  deg_sm_k<<<(NNODES + 15) / 16, 256, 0, stream>>>(A, row_ptr, c, dvB);
  prop_k<1, false><<<NNODES / 4, 256, 0, stream>>>(
      Pb0, (float4*)ego1, dvB, nv0, row_ptr, csr_t, c, A,
      (const float4*)ego0, (const float4*)ego1, (float4*)o1, Pb1, nv1);

  deg_sm_k<<<(NNODES + 15) / 16, 256, 0, stream>>>(A, row_ptr, c, dvA);
  prop_k<0, false><<<NNODES / 4, 256, 0, stream>>>(
      Pb1, (float4*)ego1, dvA, nv1, row_ptr, csr_t, c, A,
      (const float4*)ego0, (const float4*)ego1, (float4*)o1, Pb1, nv1);

  deg_sm_k<<<(NNODES + 15) / 16, 256, 0, stream>>>(A, row_ptr, c, dvB);
  prop_k<2, false><<<NNODES / 4, 256, 0, stream>>>(
      Pb1, (float4*)ego1, dvB, nv1, row_ptr, csr_t, c, A,
      (const float4*)ego0, (const float4*)ego1, (float4*)o1, Pb1, nv1);

  // duplicate (u_g, i_g) into the second output pair
  hipMemcpyAsync(o2, o1, sizeof(float) * (size_t)NNODES * EMBD,
                 hipMemcpyDeviceToDevice, stream);
}

// Round 14
// 1240.783 us; speedup vs baseline: 1.3673x; 1.3673x over previous
//
#include <hip/hip_runtime.h>
#include <cmath>

#define GS_LOOP(i, n) for (int i = blockIdx.x * blockDim.x + threadIdx.x; i < (n); i += gridDim.x * blockDim.x)

constexpr int NUSERS = 50000;
constexpr int NNODES = 100000;
constexpr int EMBD   = 128;
constexpr int NEDGE  = 2000000;
constexpr int NSCAN  = (NNODES + 1023) / 1024;   // 98

typedef float          v4f   __attribute__((ext_vector_type(4)));
typedef unsigned short v4u16 __attribute__((ext_vector_type(4)));

__device__ __forceinline__ float bf2f(unsigned short u) {
  union { unsigned int i; float f; } v; v.i = ((unsigned int)u) << 16; return v.f;
}
__device__ __forceinline__ unsigned short f2bf(float x) {
  union { float f; unsigned int i; } v; v.f = x;
  unsigned int r = v.i + 0x7FFFu + ((v.i >> 16) & 1u);   // round to nearest even
  return (unsigned short)(r >> 16);
}
// tanh(y/||.||) with nvs = 2*log2e/||.|| : 1 - 2/(exp2(y*nvs)+1)
__device__ __forceinline__ float tnh(unsigned short u, float nvs) {
  const float E = exp2f(bf2f(u) * nvs);
  return 1.f - 2.f * __builtin_amdgcn_rcpf(E + 1.f);
}
constexpr float TSCL = 2.f * 1.44269504088896f;   // 2*log2(e)

// ---------------- init (row-oriented): ego0 + Pb0 + nv0 in one read ----------------
__global__ __launch_bounds__(256) void init_k(const float4* __restrict__ ue4,
                                              const float4* __restrict__ ie4,
                                              float4* __restrict__ ego0,
                                              ushort4* __restrict__ Pb0,
                                              float* __restrict__ nv0) {
  const int j = threadIdx.x & 31;
  const int u = blockIdx.x * 8 + (threadIdx.x >> 5);
  if (u >= NNODES) return;
  const float4 y = (u < NUSERS) ? ue4[(size_t)u * 32 + j]
                                : ie4[(size_t)(u - NUSERS) * 32 + j];
  ego0[(size_t)u * 32 + j] = y;
  Pb0[(size_t)u * 32 + j] = make_ushort4(f2bf(y.x), f2bf(y.y), f2bf(y.z), f2bf(y.w));
  float ss = y.x * y.x + y.y * y.y + y.z * y.z + y.w * y.w;
  ss += __shfl_xor(ss, 1, 64);
  ss += __shfl_xor(ss, 2, 64);
  ss += __shfl_xor(ss, 4, 64);                  // 8-lane factor-group reduce
  const float inv = 1.f / fmaxf(sqrtf(ss), 1e-12f);
  if ((j & 7) == 0) nv0[u * 4 + (j >> 3)] = TSCL * inv;
}

// ---------------- CSR build ----------------
__global__ void hist_k(const int* __restrict__ h, int* __restrict__ counts) {
  GS_LOOP(e, NEDGE) atomicAdd(&counts[h[e]], 1);
}

// hierarchical scan: per-block inclusive scan + block sums
__global__ __launch_bounds__(1024) void scan1_k(const int* __restrict__ counts,
                                                int* __restrict__ part,
                                                int* __restrict__ bsum) {
  __shared__ int wsum[16];
  const int tid = threadIdx.x, lane = tid & 63, wid = tid >> 6;
  const int i = blockIdx.x * 1024 + tid;
  int v = (i < NNODES) ? counts[i] : 0;
  #pragma unroll
  for (int off = 1; off < 64; off <<= 1) {
    int y = __shfl_up(v, off, 64);
    if (lane >= off) v += y;
  }
  if (lane == 63) wsum[wid] = v;
  __syncthreads();
  if (wid == 0) {
    int w = (lane < 16) ? wsum[lane] : 0;
    #pragma unroll
    for (int off = 1; off < 16; off <<= 1) {
      int y = __shfl_up(w, off, 64);
      if (lane >= off) w += y;
    }
    if (lane < 16) wsum[lane] = w;
  }
  __syncthreads();
  const int incl = v + (wid ? wsum[wid - 1] : 0);
  if (i < NNODES) part[i] = incl;
  if (tid == 1023) bsum[blockIdx.x] = incl;
}

__global__ __launch_bounds__(128) void scan2_k(const int* __restrict__ bsum,
                                               int* __restrict__ boff) {
  __shared__ int s0[128], s1[128];
  const int tid = threadIdx.x;
  s0[tid] = (tid < NSCAN) ? bsum[tid] : 0;
  __syncthreads();
  int* a = s0; int* b = s1;
  for (int off = 1; off < 128; off <<= 1) {
    const int val = a[tid] + ((tid >= off) ? a[tid - off] : 0);
    b[tid] = val;
    __syncthreads();
    int* tmp = a; a = b; b = tmp;
  }
  boff[tid] = (tid == 0) ? 0 : a[tid - 1];
}

// also derives pass-0 d_inv analytically: softmax(ones)=0.25 -> deg0 = 0.25*count
__global__ __launch_bounds__(1024) void scan3_k(const int* __restrict__ part,
                                                const int* __restrict__ boff,
                                                const int* __restrict__ counts,
                                                int* __restrict__ row_ptr,
                                                float* __restrict__ dv0) {
  const int i = blockIdx.x * 1024 + threadIdx.x;
  if (i < NNODES) {
    row_ptr[i + 1] = part[i] + boff[blockIdx.x];
    const float d = rsqrtf(fmaxf(0.25f * (float)counts[i], 1e-12f));
    v4f w = {d, d, d, d};
    *((v4f*)dv0 + i) = w;
  }
  if (i == 0) row_ptr[0] = 0;
}

// edge identity irrelevant downstream (A lives in CSR order): store only t
__global__ void fill_k(const int* __restrict__ h, const int* __restrict__ t,
                       const int* __restrict__ row_ptr, int* __restrict__ cur,
                       int* __restrict__ csr_t) {
  GS_LOOP(e, NEDGE) {
    int u = h[e];
    int pos = row_ptr[u] + atomicAdd(&cur[u], 1);
    csr_t[pos] = t[e];
  }
}

// ---------------- per-pass: softmax(A)->c (bf16, csr order) + d_inv, 16 lanes/node ----------------
__global__ __launch_bounds__(256) void deg_sm_k(const float* __restrict__ A,
                                                const int* __restrict__ row_ptr,
                                                unsigned short* __restrict__ c,
                                                float* __restrict__ dv) {
  const float4* A4 = (const float4*)A;
  ushort4* c4 = (ushort4*)c;
  const int g = threadIdx.x >> 4;
  const int lane16 = threadIdx.x & 15;
  const int u = blockIdx.x * 16 + g;
  if (u >= NNODES) return;
  const int beg = row_ptr[u], end = row_ptr[u + 1];
  float4 acc = make_float4(0.f, 0.f, 0.f, 0.f);
  for (int p = beg + lane16; p < end; p += 16) {
    float4 a = A4[p];
    float m = fmaxf(fmaxf(a.x, a.y), fmaxf(a.z, a.w));
    float e0 = __expf(a.x - m), e1 = __expf(a.y - m);
    float e2 = __expf(a.z - m), e3 = __expf(a.w - m);
    float inv = 1.f / (e0 + e1 + e2 + e3);
    float4 s = make_float4(e0 * inv, e1 * inv, e2 * inv, e3 * inv);
    c4[p] = make_ushort4(f2bf(s.x), f2bf(s.y), f2bf(s.z), f2bf(s.w));
    acc.x += s.x; acc.y += s.y; acc.z += s.z; acc.w += s.w;
  }
  #pragma unroll
  for (int m = 1; m < 16; m <<= 1) {
    acc.x += __shfl_xor(acc.x, m, 64);
    acc.y += __shfl_xor(acc.y, m, 64);
    acc.z += __shfl_xor(acc.z, m, 64);
    acc.w += __shfl_xor(acc.w, m, 64);
  }
  if (lane16 == 0)
    ((float4*)dv)[u] = make_float4(rsqrtf(fmaxf(acc.x, 1e-12f)),
                                   rsqrtf(fmaxf(acc.y, 1e-12f)),
                                   rsqrtf(fmaxf(acc.z, 1e-12f)),
                                   rsqrtf(fmaxf(acc.w, 1e-12f)));
}

// ---------------- fused propagate + score update (wave per node, bf16 gathers) ----------------
// Single gather table: loop 2 re-reads the SAME Pb rows loop 1 fetched (L2-warm, ~µs gap),
// computing tanh on the fly from the per-node chunk-norm scale table nv. No LDS, no Tnb.
// MODE: 0 = score only; 1 = score + write Q(f32) + Pb1/nv1 tables; 2 = mean output to o1
// FIRST: pass 0 (A implicitly 1.0, scores uniform 0.25, c never read)
template <int MODE, bool FIRST>
__global__ __launch_bounds__(256) void prop_k(
    const ushort4* __restrict__ Pb4, float4* __restrict__ Q4,
    const float* __restrict__ dv_in, const float* __restrict__ nv_in,
    const int* __restrict__ row_ptr, const int* __restrict__ csr_t,
    const unsigned short* __restrict__ c, float* __restrict__ A,
    const float4* __restrict__ e0_4, const float4* __restrict__ e1_4,
    float4* __restrict__ o1_4, ushort4* __restrict__ Pb1w,
    float* __restrict__ nv1w) {
  const int u = blockIdx.x * 4 + (threadIdx.x >> 6);
  const int l = threadIdx.x & 63;
  const int half = l >> 5;     // which of 2 edges per iteration
  const int j = l & 31;        // float4 column
  const int f = j >> 3;        // factor
  const int beg = row_ptr[u], end = row_ptr[u + 1];

  // loop 1: x[u] = d_inv[u] * sum_p c[p][f] * d_inv[t_p][f] * Pb[t_p]
  float4 acc = make_float4(0.f, 0.f, 0.f, 0.f);
  int p = beg + half;
  for (; p + 14 < end; p += 16) {              // manual unroll x8: 8 row gathers in flight
    const int t0 = csr_t[p],      t1 = csr_t[p + 2];
    const int t2 = csr_t[p + 4],  t3 = csr_t[p + 6];
    const int t4 = csr_t[p + 8],  t5 = csr_t[p + 10];
    const int t6 = csr_t[p + 12], t7 = csr_t[p + 14];
    const ushort4 y0 = Pb4[(size_t)t0 * 32 + j];
    const ushort4 y1 = Pb4[(size_t)t1 * 32 + j];
    const ushort4 y2 = Pb4[(size_t)t2 * 32 + j];
    const ushort4 y3 = Pb4[(size_t)t3 * 32 + j];
    const ushort4 y4 = Pb4[(size_t)t4 * 32 + j];
    const ushort4 y5 = Pb4[(size_t)t5 * 32 + j];
    const ushort4 y6 = Pb4[(size_t)t6 * 32 + j];
    const ushort4 y7 = Pb4[(size_t)t7 * 32 + j];
    const float c0 = (FIRST ? 0.25f : bf2f(__builtin_nontemporal_load(c + (size_t)p * 4 + f)))        * dv_in[t0 * 4 + f];
    const float c1 = (FIRST ? 0.25f : bf2f(__builtin_nontemporal_load(c + (size_t)(p + 2) * 4 + f)))  * dv_in[t1 * 4 + f];
    const float c2 = (FIRST ? 0.25f : bf2f(__builtin_nontemporal_load(c + (size_t)(p + 4) * 4 + f)))  * dv_in[t2 * 4 + f];
    const float c3 = (FIRST ? 0.25f : bf2f(__builtin_nontemporal_load(c + (size_t)(p + 6) * 4 + f)))  * dv_in[t3 * 4 + f];
    const float c4_ = (FIRST ? 0.25f : bf2f(__builtin_nontemporal_load(c + (size_t)(p + 8) * 4 + f))) * dv_in[t4 * 4 + f];
    const float c5 = (FIRST ? 0.25f : bf2f(__builtin_nontemporal_load(c + (size_t)(p + 10) * 4 + f))) * dv_in[t5 * 4 + f];
    const float c6 = (FIRST ? 0.25f : bf2f(__builtin_nontemporal_load(c + (size_t)(p + 12) * 4 + f))) * dv_in[t6 * 4 + f];
    const float c7 = (FIRST ? 0.25f : bf2f(__builtin_nontemporal_load(c + (size_t)(p + 14) * 4 + f))) * dv_in[t7 * 4 + f];
    acc.x += c0 * bf2f(y0.x) + c1 * bf2f(y1.x) + c2 * bf2f(y2.x) + c3 * bf2f(y3.x)
           + c4_ * bf2f(y4.x) + c5 * bf2f(y5.x) + c6 * bf2f(y6.x) + c7 * bf2f(y7.x);
    acc.y += c0 * bf2f(y0.y) + c1 * bf2f(y1.y) + c2 * bf2f(y2.y) + c3 * bf2f(y3.y)
           + c4_ * bf2f(y4.y) + c5 * bf2f(y5.y) + c6 * bf2f(y6.y) + c7 * bf2f(y7.y);
    acc.z += c0 * bf2f(y0.z) + c1 * bf2f(y1.z) + c2 * bf2f(y2.z) + c3 * bf2f(y3.z)
           + c4_ * bf2f(y4.z) + c5 * bf2f(y5.z) + c6 * bf2f(y6.z) + c7 * bf2f(y7.z);
    acc.w += c0 * bf2f(y0.w) + c1 * bf2f(y1.w) + c2 * bf2f(y2.w) + c3 * bf2f(y3.w)
           + c4_ * bf2f(y4.w) + c5 * bf2f(y5.w) + c6 * bf2f(y6.w) + c7 * bf2f(y7.w);
  }
  for (; p < end; p += 2) {                    // tail
    const int tn = csr_t[p];
    const float cf = (FIRST ? 0.25f : bf2f(__builtin_nontemporal_load(c + (size_t)p * 4 + f))) * dv_in[tn * 4 + f];
    const ushort4 y = Pb4[(size_t)tn * 32 + j];
    acc.x += cf * bf2f(y.x); acc.y += cf * bf2f(y.y);
    acc.z += cf * bf2f(y.z); acc.w += cf * bf2f(y.w);
  }
  acc.x += __shfl_xor(acc.x, 32, 64);
  acc.y += __shfl_xor(acc.y, 32, 64);
  acc.z += __shfl_xor(acc.z, 32, 64);
  acc.w += __shfl_xor(acc.w, 32, 64);
  const float du = dv_in[u * 4 + f];
  const float4 x = make_float4(acc.x * du, acc.y * du, acc.z * du, acc.w * du);

  if (MODE == 2) {                             // final pass: write mean(e0,e1,x) to o1
    if (half == 0) {
      const v4f a = __builtin_nontemporal_load((const v4f*)e0_4 + (size_t)u * 32 + j);
      const v4f b = __builtin_nontemporal_load((const v4f*)e1_4 + (size_t)u * 32 + j);
      v4f r = {(a.x + b.x + x.x) * (1.f / 3.f), (a.y + b.y + x.y) * (1.f / 3.f),
               (a.z + b.z + x.z) * (1.f / 3.f), (a.w + b.w + x.w) * (1.f / 3.f)};
      __builtin_nontemporal_store(r, (v4f*)o1_4 + (size_t)u * 32 + j);
    }
    return;
  }
  if (MODE == 1 && half == 0) {
    v4f xq = {x.x, x.y, x.z, x.w};
    __builtin_nontemporal_store(xq, (v4f*)Q4 + (size_t)u * 32 + j);
    v4u16 pb = {f2bf(x.x), f2bf(x.y), f2bf(x.z), f2bf(x.w)};
    __builtin_nontemporal_store(pb, (v4u16*)Pb1w + (size_t)u * 32 + j);
  }

  // chunk l2-norm of x (8-lane factor group)
  float ss = x.x * x.x + x.y * x.y + x.z * x.z + x.w * x.w;
  ss += __shfl_xor(ss, 1, 64);
  ss += __shfl_xor(ss, 2, 64);
  ss += __shfl_xor(ss, 4, 64);
  const float inv = 1.f / fmaxf(sqrtf(ss), 1e-12f);
  const float4 xn = make_float4(x.x * inv, x.y * inv, x.z * inv, x.w * inv);
  if (MODE == 1 && half == 0 && (j & 7) == 0) nv1w[u * 4 + f] = TSCL * inv;

  // loop 2: A[p][f] += dot(xn, tanh(Pb[t]*ninv[t]))  -- Pb rows L2-warm from loop 1
  int q = beg + half;
  for (; q + 6 < end; q += 8) {                // manual unroll x4
    const int t0 = csr_t[q],     t1 = csr_t[q + 2];
    const int t2 = csr_t[q + 4], t3 = csr_t[q + 6];
    const ushort4 b0 = Pb4[(size_t)t0 * 32 + j];
    const ushort4 b1 = Pb4[(size_t)t1 * 32 + j];
    const ushort4 b2 = Pb4[(size_t)t2 * 32 + j];
    const ushort4 b3 = Pb4[(size_t)t3 * 32 + j];
    const float n0 = nv_in[t0 * 4 + f], n1 = nv_in[t1 * 4 + f];
    const float n2 = nv_in[t2 * 4 + f], n3 = nv_in[t3 * 4 + f];
    float s0 = xn.x * tnh(b0.x, n0) + xn.y * tnh(b0.y, n0)
             + xn.z * tnh(b0.z, n0) + xn.w * tnh(b0.w, n0);
    float s1 = xn.x * tnh(b1.x, n1) + xn.y * tnh(b1.y, n1)
             + xn.z * tnh(b1.z, n1) + xn.w * tnh(b1.w, n1);
    float s2 = xn.x * tnh(b2.x, n2) + xn.y * tnh(b2.y, n2)
             + xn.z * tnh(b2.z, n2) + xn.w * tnh(b2.w, n2);
    float s3 = xn.x * tnh(b3.x, n3) + xn.y * tnh(b3.y, n3)
             + xn.z * tnh(b3.z, n3) + xn.w * tnh(b3.w, n3);
    #pragma unroll
    for (int m = 1; m < 8; m <<= 1) {
      s0 += __shfl_xor(s0, m, 64); s1 += __shfl_xor(s1, m, 64);
      s2 += __shfl_xor(s2, m, 64); s3 += __shfl_xor(s3, m, 64);
    }
    if ((j & 7) == 0) {
      if (FIRST) {
        A[(size_t)q * 4 + f] = 1.f + s0;
        A[(size_t)(q + 2) * 4 + f] = 1.f + s1;
        A[(size_t)(q + 4) * 4 + f] = 1.f + s2;
        A[(size_t)(q + 6) * 4 + f] = 1.f + s3;
      } else {
        A[(size_t)q * 4 + f] += s0;
        A[(size_t)(q + 2) * 4 + f] += s1;
        A[(size_t)(q + 4) * 4 + f] += s2;
        A[(size_t)(q + 6) * 4 + f] += s3;
      }
    }
  }
  for (; q < end; q += 2) {                    // tail
    const int tn = csr_t[q];
    const ushort4 tb = Pb4[(size_t)tn * 32 + j];
    const float nn = nv_in[tn * 4 + f];
    float s = xn.x * tnh(tb.x, nn) + xn.y * tnh(tb.y, nn)
            + xn.z * tnh(tb.z, nn) + xn.w * tnh(tb.w, nn);
    s += __shfl_xor(s, 1, 64);
    s += __shfl_xor(s, 2, 64);
    s += __shfl_xor(s, 4, 64);
    if ((j & 7) == 0) {
      if (FIRST) A[(size_t)q * 4 + f] = 1.f + s;
      else       A[(size_t)q * 4 + f] += s;
    }
  }
}

extern "C" void kernel_launch(void* const* d_in, const int* in_sizes, int n_in,
                              void* d_out, int out_size, void* d_ws, size_t ws_size,
                              hipStream_t stream) {
  const float* ue = (const float*)d_in[0];
  const float* ie = (const float*)d_in[1];
  const int* h = (const int*)d_in[2];
  const int* t = (const int*)d_in[3];
  float* out = (float*)d_out;
  char* ws = (char*)d_ws;

  size_t off = 0;
  auto alloc = [&](size_t bytes) -> void* {
    void* p = ws + off;
    off += (bytes + 255) & ~size_t(255);
    return p;
  };
  float* ego0  = (float*)alloc(sizeof(float) * (size_t)NNODES * EMBD);  // 51.2 MB
  float* ego1  = (float*)alloc(sizeof(float) * (size_t)NNODES * EMBD);  // 51.2 MB
  float* A     = (float*)alloc(sizeof(float) * 4 * (size_t)NEDGE);      // 32  MB (CSR order)
  unsigned short* c = (unsigned short*)alloc(sizeof(unsigned short) * 4 * (size_t)NEDGE); // 16 MB (bf16)
  float* dvA   = (float*)alloc(sizeof(float) * NNODES * 4);             // 1.6 MB (ping)
  float* dvB   = (float*)alloc(sizeof(float) * NNODES * 4);             // 1.6 MB (pong)
  int* row_ptr = (int*)alloc(sizeof(int) * (NNODES + 1));
  int* cur     = (int*)alloc(sizeof(int) * NNODES);
  int* part    = (int*)alloc(sizeof(int) * NNODES);
  int* bsum    = (int*)alloc(sizeof(int) * 128);
  int* boff    = (int*)alloc(sizeof(int) * 128);
  int* csr_t   = (int*)alloc(sizeof(int) * NEDGE);                      // 8 MB

  // bf16 gather table + norm-scale table live in d_out halves (Pb 25.6 MB + nv 1.6 MB each).
  // Layer-1 tables in o1 (dead by pass 3, which overwrites o1);
  // layer-2 tables in o2 (read during pass 3; o2 refilled by the final d2d copy).
  float* o1 = out;
  float* o2 = out + (size_t)NNODES * EMBD;
  ushort4* Pb0 = (ushort4*)o1;
  float*   nv0 = (float*)((char*)o1 + sizeof(unsigned short) * (size_t)NNODES * EMBD);
  ushort4* Pb1 = (ushort4*)o2;
  float*   nv1 = (float*)((char*)o2 + sizeof(unsigned short) * (size_t)NNODES * EMBD);

  // setup (once per call)
  init_k<<<(NNODES + 7) / 8, 256, 0, stream>>>((const float4*)ue, (const float4*)ie,
                                               (float4*)ego0, Pb0, nv0);
  hipMemsetAsync(cur, 0, sizeof(int) * NNODES, stream);
  hist_k<<<2048, 256, 0, stream>>>(h, cur);
  scan1_k<<<NSCAN, 1024, 0, stream>>>(cur, part, bsum);
  scan2_k<<<1, 128, 0, stream>>>(bsum, boff);
  scan3_k<<<NSCAN, 1024, 0, stream>>>(part, boff, cur, row_ptr, dvA);
  hipMemsetAsync(cur, 0, sizeof(int) * NNODES, stream);
  fill_k<<<2048, 256, 0, stream>>>(h, t, row_ptr, cur, csr_t);

  // pass 0: score (analytic softmax=0.25, dv from counts)  [layer-1 tables]
  // pass 1: deg_sm(A)->c,dvB; score + Q=ego1 + Pb1/nv1     [layer-1 tables]
  // pass 2: deg_sm(A)->c,dvA; score                        [layer-2 tables]
  // pass 3: deg_sm(A)->c,dvB; mean output -> o1            [layer-2 tables]
  prop_k<0, true><<<NNODES / 4, 256, 0, stream>>>(
      Pb0, (float4*)ego1, dvA, nv0, row_ptr, csr_t, c, A,
      (const float4*)ego0, (const float4*)ego1, (float4*)o1, Pb1, nv1);

  deg_sm_k<<<(NNODES + 15) / 16, 256, 0, stream>>>(A, row_ptr, c, dvB);
  prop_k<1, false><<<NNODES / 4, 256, 0, stream>>>(
      Pb0, (float4*)ego1, dvB, nv0, row_ptr, csr_t, c, A,
      (const float4*)ego0, (const float4*)ego1, (float4*)o1, Pb1, nv1);

  deg_sm_k<<<(NNODES + 15) / 16, 256, 0, stream>>>(A, row_ptr, c, dvA);
  prop_k<0, false><<<NNODES / 4, 256, 0, stream>>>(
      Pb1, (float4*)ego1, dvA, nv1, row_ptr, csr_t, c, A,
      (const float4*)ego0, (const float4*)ego1, (float4*)o1, Pb1, nv1);

  deg_sm_k<<<(NNODES + 15) / 16, 256, 0, stream>>>(A, row_ptr, c, dvB);
  prop_k<2, false><<<NNODES / 4, 256, 0, stream>>>(
      Pb1, (float4*)ego1, dvB, nv1, row_ptr, csr_t, c, A,
      (const float4*)ego0, (const float4*)ego1, (float4*)o1, Pb1, nv1);

  // duplicate (u_g, i_g) into the second output pair
  hipMemcpyAsync(o2, o1, sizeof(float) * (size_t)NNODES * EMBD,
                 hipMemcpyDeviceToDevice, stream);
}